// Round 13
// baseline (435.184 us; speedup 1.0000x reference)
//
#include <hip/hip_runtime.h>
#include <cstdint>
#include <cstddef>

typedef unsigned int u32;
typedef unsigned long long u64;

#define BB   8
#define NN   50000
#define CC   80
#define KTOP 1000
#define CAP  4096
#define NHB  129              // 128 fine buckets [0x3F00..0x3F7F] + 1 underflow
#define CLIPV 4.135166556742356f

// ---- workspace layout (bytes), total ~4.72 MB ----
#define OFF_KEYS 0UL          // u32 [B*N]
#define OFF_CLS  1600000UL    // i32 [B*N]
#define OFF_HIST 3200000UL    // u32 [B*129]
#define OFF_CNT  3204128UL    // u32 [B*16] (64-B stride per image)
#define OFF_CAND 3204640UL    // u64 [B*CAP]
#define OFF_TKEY 3466784UL    // u32 [B*K]
#define OFF_TIDX 3498784UL    // u32 [B*K]
#define OFF_BOX  3530784UL    // f32 [B*K*4]
#define OFF_AREA 3658784UL    // f32 [B*K]
#define OFF_MAT  3690784UL    // u64 [B*K*16]
#define OFF_KEEP 4714784UL    // u64 [B*16]

// Pass 1: LDS-staged coalesced max/argmax + LDS histogram, aggregated flush.
__global__ __launch_bounds__(256) void k_scores_u(const float4* __restrict__ labels4,
                                                  u32* __restrict__ keys,
                                                  int* __restrict__ cls,
                                                  u32* __restrict__ ghist) {
    __shared__ float4 tile[64 * 21];          // pad-21: stage s -> s + s/20
    __shared__ float  pbest[3][64];
    __shared__ int    pcls[3][64];
    __shared__ u32    lhist[NHB];
    int t = threadIdx.x;
    int img = blockIdx.x / 196;
    int blk = blockIdx.x - img * 196;
    size_t img_base = (size_t)img * NN * 20;  // float4 units
    for (int i = t; i < NHB; i += 256) lhist[i] = 0;
    int a = t & 63;
    int q = t >> 6;
#pragma unroll
    for (int tl = 0; tl < 4; ++tl) {
        int na0 = blk * 256 + tl * 64;
        int nv = NN - na0; if (nv > 64) nv = 64; if (nv < 0) nv = 0;
        int lim = nv * 20;
#pragma unroll
        for (int i = 0; i < 5; ++i) {
            int s = i * 256 + t;
            if (s < lim) {
                float4 v = labels4[img_base + (size_t)na0 * 20 + s];
                tile[s + s / 20] = v;
            }
        }
        __syncthreads();
        float best = -1.0e30f; int bc = 0;
        if (a < nv) {
#pragma unroll
            for (int j = 0; j < 5; ++j) {
                float4 v = tile[a * 21 + q * 5 + j];
                int c = q * 20 + j * 4;
                if (v.x > best) { best = v.x; bc = c; }
                if (v.y > best) { best = v.y; bc = c + 1; }
                if (v.z > best) { best = v.z; bc = c + 2; }
                if (v.w > best) { best = v.w; bc = c + 3; }
            }
            if (q > 0) { pbest[q - 1][a] = best; pcls[q - 1][a] = bc; }
        }
        __syncthreads();
        if (q == 0 && a < nv) {
#pragma unroll
            for (int r = 0; r < 3; ++r) {     // ascending class order, strict >
                float pb = pbest[r][a];
                if (pb > best) { best = pb; bc = pcls[r][a]; }
            }
            int g = img * NN + na0 + a;
            float score = 1.0f / (1.0f + expf(-best));
            bool fg = (bc != 0) && (score > 0.05f);
            u32 key = fg ? __float_as_uint(score) : 0u;
            keys[g] = key;
            cls[g] = bc;
            u32 kb = key >> 16;
            u32 idx = (kb >= 0x3F00u) ? (kb - 0x3F00u) : 128u;
            atomicAdd(&lhist[idx], 1u);
        }
        __syncthreads();
    }
    for (int i = t; i < NHB; i += 256) {
        u32 c = lhist[i];
        if (c) atomicAdd(&ghist[img * NHB + i], c);
    }
}

// Pass 2: candidate compaction with in-block threshold (shfl-scan of 128 buckets).
__global__ __launch_bounds__(256) void k_gather(const u32* __restrict__ keys,
                                                const u32* __restrict__ ghist,
                                                u32* __restrict__ cnt,
                                                u64* __restrict__ cand) {
    __shared__ u32 wsum[4];
    __shared__ u32 bbase;
    __shared__ u32 sT16;
    __shared__ u32 wtot;
    int t = threadIdx.x;
    int img = blockIdx.x / 196;
    int blk = blockIdx.x - img * 196;

    u32 v = 0;
    if (t < 128) v = ghist[img * NHB + (127 - t)];   // tid asc == bucket desc
    u32 incl = v;
#pragma unroll
    for (int d = 1; d < 64; d <<= 1) {
        u32 up = __shfl_up(incl, (unsigned)d);       // width 64
        if ((t & 63) >= d) incl += up;
    }
    if (t == 63) wtot = incl;
    __syncthreads();
    if (t >= 64 && t < 128) incl += wtot;
    if (t < 128) {
        u32 excl = incl - v;
        if (excl < KTOP && incl >= KTOP) sT16 = 0x3F00u + 127u - (u32)t;  // unique crossing
    }
    if (t == 127 && incl < KTOP) sT16 = 0x3F00u;     // total < K: take all fine buckets
    __syncthreads();
    u32 T16 = sT16;

    int n = blk * 256 + t;
    u32 key = 0; bool pass = false;
    if (n < NN) {
        key = keys[img * NN + n];
        pass = (key >> 16) >= T16;
    }
    u64 mask = __ballot(pass);
    int lane = t & 63, wid = t >> 6;
    u32 prefix = (u32)__popcll(mask & ((1ull << lane) - 1ull));
    if (lane == 0) wsum[wid] = (u32)__popcll(mask);
    __syncthreads();
    if (t == 0) {
        u32 s0 = wsum[0], s1 = wsum[1], s2 = wsum[2], s3 = wsum[3];
        u32 tot = s0 + s1 + s2 + s3;
        bbase = tot ? atomicAdd(&cnt[img * 16], tot) : 0u;
        wsum[0] = 0; wsum[1] = s0; wsum[2] = s0 + s1; wsum[3] = s0 + s1 + s2;
    }
    __syncthreads();
    if (pass) {
        u32 pos = bbase + wsum[wid] + prefix;
        if (pos < CAP)
            cand[(size_t)img * CAP + pos] = ((u64)key << 32) | (u32)(~(u32)n); // ~n: idx-asc ties
    }
}

// Pass 3a: bitonic stages k=2..1024, chunk-local (global-index direction bit).
__global__ __launch_bounds__(256) void k_sortA(u64* __restrict__ cand,
                                               const u32* __restrict__ cnt) {
    __shared__ u64 sm[1024];
    int b = blockIdx.x >> 2;
    int c = blockIdx.x & 3;
    int tid = threadIdx.x;
    int m = (int)min(cnt[b * 16], (u32)CAP);
    int base = c * 1024;
    u64* cp = cand + (size_t)b * CAP;
    for (int i = tid; i < 1024; i += 256) {
        int g = base + i;
        sm[i] = (g < m) ? cp[g] : 0ull;
    }
    __syncthreads();
    for (int k = 2; k <= 1024; k <<= 1)
        for (int j = k >> 1; j > 0; j >>= 1) {
            for (int i = tid; i < 1024; i += 256) {
                int ixj = i ^ j;
                if (ixj > i) {
                    bool desc = (((base + i) & k) == 0);
                    u64 x = sm[i], y = sm[ixj];
                    if (desc ? (x < y) : (x > y)) { sm[i] = y; sm[ixj] = x; }
                }
            }
            __syncthreads();
        }
    for (int i = tid; i < 1024; i += 256) cp[base + i] = sm[i];
}

// Pass 3b: merge stages k=2048,4096 + top-K emit + box decode.
__global__ __launch_bounds__(512) void k_sortB(const u64* __restrict__ cand,
                                               const float4* __restrict__ codes,
                                               const float4* __restrict__ anchors,
                                               u32* __restrict__ tkey, u32* __restrict__ tidx,
                                               float4* __restrict__ boxes, float* __restrict__ area) {
    __shared__ u64 sm[CAP];
    int b = blockIdx.x, tid = threadIdx.x;
    const u64* cp = cand + (size_t)b * CAP;
    for (int i = tid; i < CAP; i += 512) sm[i] = cp[i];   // A wrote padded zeros
    __syncthreads();
    for (int k = 2048; k <= 4096; k <<= 1)
        for (int j = k >> 1; j > 0; j >>= 1) {
            for (int i = tid; i < CAP; i += 512) {
                int ixj = i ^ j;
                if (ixj > i) {
                    bool desc = ((i & k) == 0);
                    u64 x = sm[i], y = sm[ixj];
                    if (desc ? (x < y) : (x > y)) { sm[i] = y; sm[ixj] = x; }
                }
            }
            __syncthreads();
        }
#pragma unroll
    for (int r = 0; r < 2; ++r) {
        int i = r * 512 + tid;
        if (i < KTOP) {
            u64 v = sm[i];
            u32 kb = (u32)(v >> 32);
            u32 n = ~(u32)v;
            if (kb == 0u) n = 0u;
            int g = b * KTOP + i;
            tkey[g] = kb; tidx[g] = n;
            float4 a = anchors[(size_t)b * NN + n];
            float4 cc = codes[(size_t)b * NN + n];
            float w = a.z - a.x, h = a.w - a.y;
            float cx = a.x + 0.5f * w, cy = a.y + 0.5f * h;
            float dw = fminf(cc.z, CLIPV), dh = fminf(cc.w, CLIPV);
            float pcx = cc.x * w + cx, pcy = cc.y * h + cy;
            float pw = expf(dw) * w, ph = expf(dh) * h;
            float x0 = pcx - 0.5f * pw, y0 = pcy - 0.5f * ph;
            float x1 = pcx + 0.5f * pw, y1 = pcy + 0.5f * ph;
            boxes[g] = make_float4(x0, y0, x1, y1);
            area[g] = (x1 - x0) * (y1 - y0);
        }
    }
}

// Pass 4: suppression bit-matrix via LDS-staged j-chunks (128 blocks).
__global__ __launch_bounds__(256) void k_mat(const float4* __restrict__ boxes,
                                             const float* __restrict__ area,
                                             u64* __restrict__ mat) {
    __shared__ float4 sb[256];
    __shared__ float  sa[256];
    int bid = blockIdx.x;
    int wc = bid & 3, rc = (bid >> 2) & 3, b = bid >> 4;
    int t = threadIdx.x;
    int j0 = wc * 256;
    int jn = min(256, KTOP - j0);
    if (t < jn) { sb[t] = boxes[b * KTOP + j0 + t]; sa[t] = area[b * KTOP + j0 + t]; }
    __syncthreads();
    if (t >= 250) return;
    int i = rc * 250 + t;
    float4 bi = boxes[b * KTOP + i];
    float ai = area[b * KTOP + i];
    u64 w[4] = {0ull, 0ull, 0ull, 0ull};
    int estart = i - j0 + 1; if (estart < 0) estart = 0;
    for (int e = estart; e < jn; ++e) {
        float4 bj = sb[e];
        float lx = fmaxf(bi.x, bj.x), ly = fmaxf(bi.y, bj.y);
        float rx = fminf(bi.z, bj.z), ry = fminf(bi.w, bj.w);
        float ww = fmaxf(rx - lx, 0.0f), hh = fmaxf(ry - ly, 0.0f);
        float inter = ww * hh;
        float iou = inter / (ai + sa[e] - inter + 1e-9f);
        if (iou > 0.5f) w[e >> 6] |= (1ull << (e & 63));
    }
    u64* outp = &mat[((size_t)(b * KTOP + i)) * 16 + wc * 4];
    outp[0] = w[0]; outp[1] = w[1]; outp[2] = w[2]; outp[3] = w[3];
}

// Pass 5: NMS, shuffle-based, zero LDS on the critical path.
// One wave per image. Phase p (rows p*64..p*64+63): lane e holds row p*64+e
// fully in registers. The keep words kw[0..15] are REPLICATED in all lanes and
// updated uniformly:
//  - serial walk over word p: step e broadcasts row e's word p via __shfl and
//    applies it under a uniform predicate ((kw[p]>>e)&1) -- exact fori_loop
//    order within the word, no divergence, no memory on the chain.
//  - cross-word (w>p): suppression = OR over applied rows of their word w,
//    computed as a 6-step __shfl_xor OR-reduction (deferred apply is safe:
//    word w's bits are only consulted in phase w > p).
__global__ __launch_bounds__(64) void k_nms2(const u64* __restrict__ mat,
                                             u64* __restrict__ keepw) {
    int b = blockIdx.x, lane = threadIdx.x;
    const u64* mb = mat + (size_t)b * (KTOP * 16);
    u64 kw[16];
#pragma unroll
    for (int w = 0; w < 15; ++w) kw[w] = ~0ull;
    kw[15] = (1ull << 40) - 1;                 // bits 960..999 valid
    for (int p = 0; p < 16; ++p) {
        int row = p * 64 + lane;
        u64 r[16];
        if (row < KTOP) {
            const u64* rp = mb + (size_t)row * 16;
#pragma unroll
            for (int w = 0; w < 16; ++w) r[w] = rp[w];
        } else {
#pragma unroll
            for (int w = 0; w < 16; ++w) r[w] = 0ull;
        }
        // ---- serial walk over word p (uniform across lanes) ----
        u64 kwp = kw[p];
        u64 applied = 0;
        u64 myp = r[p];
#pragma unroll 1
        for (int e = 0; e < 64; ++e) {
            if ((kwp >> e) & 1ull) {           // uniform predicate
                u64 s = __shfl(myp, e);        // row e's word p -> all lanes
                kwp &= ~s;
                applied |= (1ull << e);
            }
        }
        kw[p] = kwp;
        // ---- cross-word apply via OR-reduction ----
        bool mine = (applied >> lane) & 1ull;  // my row was applied
        for (int w = p + 1; w < 16; ++w) {
            u64 v = mine ? r[w] : 0ull;
#pragma unroll
            for (int d = 32; d > 0; d >>= 1) v |= __shfl_xor(v, d);
            kw[w] &= ~v;
        }
    }
    if (lane < 16) keepw[b * 16 + lane] = kw[lane];
}

// Pass 6: final masked outputs (parallel, 32 blocks).
__global__ __launch_bounds__(256) void k_out(const u64* __restrict__ keepw,
                                             const u32* __restrict__ tkey,
                                             const u32* __restrict__ tidx,
                                             const int* __restrict__ cls,
                                             const float4* __restrict__ boxes,
                                             float* __restrict__ out) {
    int gid = blockIdx.x * 256 + threadIdx.x;
    if (gid >= BB * KTOP) return;
    int b = gid / KTOP;
    int k = gid - b * KTOP;
    u64 kwv = keepw[b * 16 + (k >> 6)];
    bool kp = (kwv >> (k & 63)) & 1ull;
    float sc = __uint_as_float(tkey[gid]);
    kp = kp && (sc > 0.0f);
    int cl = cls[(size_t)b * NN + tidx[gid]];
    float4 bx = boxes[gid];
    const int BK = BB * KTOP;
    out[gid] = kp ? (float)cl : -1.0f;                 // out_cls
    out[BK + gid] = kp ? sc : 0.0f;                    // out_scores
    float* ob = out + 2 * BK + (size_t)gid * 4;        // out_boxes
    ob[0] = kp ? bx.x : 0.0f;
    ob[1] = kp ? bx.y : 0.0f;
    ob[2] = kp ? bx.z : 0.0f;
    ob[3] = kp ? bx.w : 0.0f;
    out[6 * BK + gid] = kp ? 1.0f : 0.0f;              // keep
}

extern "C" void kernel_launch(void* const* d_in, const int* in_sizes, int n_in,
                              void* d_out, int out_size, void* d_ws, size_t ws_size,
                              hipStream_t stream) {
    const float* labels  = (const float*)d_in[0];
    const float* codes   = (const float*)d_in[1];
    const float* anchors = (const float*)d_in[2];
    char* ws = (char*)d_ws;
    u32* keys  = (u32*)(ws + OFF_KEYS);
    int* cls   = (int*)(ws + OFF_CLS);
    u32* hist  = (u32*)(ws + OFF_HIST);
    u32* cnt   = (u32*)(ws + OFF_CNT);
    u64* cand  = (u64*)(ws + OFF_CAND);
    u32* tkey  = (u32*)(ws + OFF_TKEY);
    u32* tidx  = (u32*)(ws + OFF_TIDX);
    float4* bx = (float4*)(ws + OFF_BOX);
    float* ar  = (float*)(ws + OFF_AREA);
    u64* mat   = (u64*)(ws + OFF_MAT);
    u64* kpw   = (u64*)(ws + OFF_KEEP);

    // zero hist + cnt (4640 B; ws re-poisoned 0xAA before every timed launch)
    hipMemsetAsync(ws + OFF_HIST, 0, OFF_CAND - OFF_HIST, stream);

    k_scores_u<<<BB * 196, 256, 0, stream>>>((const float4*)labels, keys, cls, hist);
    k_gather<<<BB * 196, 256, 0, stream>>>(keys, hist, cnt, cand);
    k_sortA<<<BB * 4, 256, 0, stream>>>(cand, cnt);
    k_sortB<<<BB, 512, 0, stream>>>(cand, (const float4*)codes, (const float4*)anchors,
                                    tkey, tidx, bx, ar);
    k_mat<<<BB * 16, 256, 0, stream>>>(bx, ar, mat);
    k_nms2<<<BB, 64, 0, stream>>>(mat, kpw);
    k_out<<<(BB * KTOP + 255) / 256, 256, 0, stream>>>(kpw, tkey, tidx, cls, bx, (float*)d_out);
}

// Round 15
// 361.213 us; speedup vs baseline: 1.2048x; 1.2048x over previous
//
#include <hip/hip_runtime.h>
#include <cstdint>
#include <cstddef>

typedef unsigned int u32;
typedef unsigned long long u64;

#define BB   8
#define NN   50000
#define CC   80
#define KTOP 1000
#define CAP  4096
#define NHB  129              // 128 fine buckets [0x3F00..0x3F7F] + 1 underflow
#define CLIPV 4.135166556742356f

// ---- workspace layout (bytes), total ~4.74 MB ----
#define OFF_KEYS 0UL          // u32 [B*N]
#define OFF_CLS  1600000UL    // i32 [B*N]
#define OFF_HIST 3200000UL    // u32 [B*129]
#define OFF_CNT  3204128UL    // u32 [B*16] (64-B stride per image)
#define OFF_CAND 3204640UL    // u64 [B*CAP]
#define OFF_TKEY 3466784UL    // u32 [B*K]
#define OFF_TIDX 3498784UL    // u32 [B*K]
#define OFF_BOX  3530784UL    // f32 [B*K*4]
#define OFF_AREA 3658784UL    // f32 [B*K]
#define OFF_MATT 3690784UL    // u64 [B*16*16*64]  (column-major bit-matrix)
#define OFF_KEEP 4739360UL    // u64 [B*16]

// Pass 1: LDS-staged coalesced max/argmax + LDS histogram, aggregated flush.
__global__ __launch_bounds__(256) void k_scores_u(const float4* __restrict__ labels4,
                                                  u32* __restrict__ keys,
                                                  int* __restrict__ cls,
                                                  u32* __restrict__ ghist) {
    __shared__ float4 tile[64 * 21];          // pad-21: stage s -> s + s/20
    __shared__ float  pbest[3][64];
    __shared__ int    pcls[3][64];
    __shared__ u32    lhist[NHB];
    int t = threadIdx.x;
    int img = blockIdx.x / 196;
    int blk = blockIdx.x - img * 196;
    size_t img_base = (size_t)img * NN * 20;  // float4 units
    for (int i = t; i < NHB; i += 256) lhist[i] = 0;
    int a = t & 63;
    int q = t >> 6;
#pragma unroll
    for (int tl = 0; tl < 4; ++tl) {
        int na0 = blk * 256 + tl * 64;
        int nv = NN - na0; if (nv > 64) nv = 64; if (nv < 0) nv = 0;
        int lim = nv * 20;
#pragma unroll
        for (int i = 0; i < 5; ++i) {
            int s = i * 256 + t;
            if (s < lim) {
                float4 v = labels4[img_base + (size_t)na0 * 20 + s];
                tile[s + s / 20] = v;
            }
        }
        __syncthreads();
        float best = -1.0e30f; int bc = 0;
        if (a < nv) {
#pragma unroll
            for (int j = 0; j < 5; ++j) {
                float4 v = tile[a * 21 + q * 5 + j];
                int c = q * 20 + j * 4;
                if (v.x > best) { best = v.x; bc = c; }
                if (v.y > best) { best = v.y; bc = c + 1; }
                if (v.z > best) { best = v.z; bc = c + 2; }
                if (v.w > best) { best = v.w; bc = c + 3; }
            }
            if (q > 0) { pbest[q - 1][a] = best; pcls[q - 1][a] = bc; }
        }
        __syncthreads();
        if (q == 0 && a < nv) {
#pragma unroll
            for (int r = 0; r < 3; ++r) {     // ascending class order, strict >
                float pb = pbest[r][a];
                if (pb > best) { best = pb; bc = pcls[r][a]; }
            }
            int g = img * NN + na0 + a;
            float score = 1.0f / (1.0f + expf(-best));
            bool fg = (bc != 0) && (score > 0.05f);
            u32 key = fg ? __float_as_uint(score) : 0u;
            keys[g] = key;
            cls[g] = bc;
            u32 kb = key >> 16;
            u32 idx = (kb >= 0x3F00u) ? (kb - 0x3F00u) : 128u;
            atomicAdd(&lhist[idx], 1u);
        }
        __syncthreads();
    }
    for (int i = t; i < NHB; i += 256) {
        u32 c = lhist[i];
        if (c) atomicAdd(&ghist[img * NHB + i], c);
    }
}

// Pass 2: candidate compaction with in-block threshold (shfl-scan of 128 buckets).
__global__ __launch_bounds__(256) void k_gather(const u32* __restrict__ keys,
                                                const u32* __restrict__ ghist,
                                                u32* __restrict__ cnt,
                                                u64* __restrict__ cand) {
    __shared__ u32 wsum[4];
    __shared__ u32 bbase;
    __shared__ u32 sT16;
    __shared__ u32 wtot;
    int t = threadIdx.x;
    int img = blockIdx.x / 196;
    int blk = blockIdx.x - img * 196;

    u32 v = 0;
    if (t < 128) v = ghist[img * NHB + (127 - t)];   // tid asc == bucket desc
    u32 incl = v;
#pragma unroll
    for (int d = 1; d < 64; d <<= 1) {
        u32 up = __shfl_up(incl, (unsigned)d);       // width 64
        if ((t & 63) >= d) incl += up;
    }
    if (t == 63) wtot = incl;
    __syncthreads();
    if (t >= 64 && t < 128) incl += wtot;
    if (t < 128) {
        u32 excl = incl - v;
        if (excl < KTOP && incl >= KTOP) sT16 = 0x3F00u + 127u - (u32)t;  // unique crossing
    }
    if (t == 127 && incl < KTOP) sT16 = 0x3F00u;     // total < K: take all fine buckets
    __syncthreads();
    u32 T16 = sT16;

    int n = blk * 256 + t;
    u32 key = 0; bool pass = false;
    if (n < NN) {
        key = keys[img * NN + n];
        pass = (key >> 16) >= T16;
    }
    u64 mask = __ballot(pass);
    int lane = t & 63, wid = t >> 6;
    u32 prefix = (u32)__popcll(mask & ((1ull << lane) - 1ull));
    if (lane == 0) wsum[wid] = (u32)__popcll(mask);
    __syncthreads();
    if (t == 0) {
        u32 s0 = wsum[0], s1 = wsum[1], s2 = wsum[2], s3 = wsum[3];
        u32 tot = s0 + s1 + s2 + s3;
        bbase = tot ? atomicAdd(&cnt[img * 16], tot) : 0u;
        wsum[0] = 0; wsum[1] = s0; wsum[2] = s0 + s1; wsum[3] = s0 + s1 + s2;
    }
    __syncthreads();
    if (pass) {
        u32 pos = bbase + wsum[wid] + prefix;
        if (pos < CAP)
            cand[(size_t)img * CAP + pos] = ((u64)key << 32) | (u32)(~(u32)n); // ~n: idx-asc ties
    }
}

// Pass 3a: bitonic stages k=2..1024, chunk-local (global-index direction bit).
__global__ __launch_bounds__(256) void k_sortA(u64* __restrict__ cand,
                                               const u32* __restrict__ cnt) {
    __shared__ u64 sm[1024];
    int b = blockIdx.x >> 2;
    int c = blockIdx.x & 3;
    int tid = threadIdx.x;
    int m = (int)min(cnt[b * 16], (u32)CAP);
    int base = c * 1024;
    u64* cp = cand + (size_t)b * CAP;
    for (int i = tid; i < 1024; i += 256) {
        int g = base + i;
        sm[i] = (g < m) ? cp[g] : 0ull;
    }
    __syncthreads();
    for (int k = 2; k <= 1024; k <<= 1)
        for (int j = k >> 1; j > 0; j >>= 1) {
            for (int i = tid; i < 1024; i += 256) {
                int ixj = i ^ j;
                if (ixj > i) {
                    bool desc = (((base + i) & k) == 0);
                    u64 x = sm[i], y = sm[ixj];
                    if (desc ? (x < y) : (x > y)) { sm[i] = y; sm[ixj] = x; }
                }
            }
            __syncthreads();
        }
    for (int i = tid; i < 1024; i += 256) cp[base + i] = sm[i];
}

// Pass 3b: merge stages k=2048,4096 + top-K emit + box decode.
__global__ __launch_bounds__(512) void k_sortB(const u64* __restrict__ cand,
                                               const float4* __restrict__ codes,
                                               const float4* __restrict__ anchors,
                                               u32* __restrict__ tkey, u32* __restrict__ tidx,
                                               float4* __restrict__ boxes, float* __restrict__ area) {
    __shared__ u64 sm[CAP];
    int b = blockIdx.x, tid = threadIdx.x;
    const u64* cp = cand + (size_t)b * CAP;
    for (int i = tid; i < CAP; i += 512) sm[i] = cp[i];   // A wrote padded zeros
    __syncthreads();
    for (int k = 2048; k <= 4096; k <<= 1)
        for (int j = k >> 1; j > 0; j >>= 1) {
            for (int i = tid; i < CAP; i += 512) {
                int ixj = i ^ j;
                if (ixj > i) {
                    bool desc = ((i & k) == 0);
                    u64 x = sm[i], y = sm[ixj];
                    if (desc ? (x < y) : (x > y)) { sm[i] = y; sm[ixj] = x; }
                }
            }
            __syncthreads();
        }
#pragma unroll
    for (int r = 0; r < 2; ++r) {
        int i = r * 512 + tid;
        if (i < KTOP) {
            u64 v = sm[i];
            u32 kb = (u32)(v >> 32);
            u32 n = ~(u32)v;
            if (kb == 0u) n = 0u;
            int g = b * KTOP + i;
            tkey[g] = kb; tidx[g] = n;
            float4 a = anchors[(size_t)b * NN + n];
            float4 cc = codes[(size_t)b * NN + n];
            float w = a.z - a.x, h = a.w - a.y;
            float cx = a.x + 0.5f * w, cy = a.y + 0.5f * h;
            float dw = fminf(cc.z, CLIPV), dh = fminf(cc.w, CLIPV);
            float pcx = cc.x * w + cx, pcy = cc.y * h + cy;
            float pw = expf(dw) * w, ph = expf(dh) * h;
            float x0 = pcx - 0.5f * pw, y0 = pcy - 0.5f * ph;
            float x1 = pcx + 0.5f * pw, y1 = pcy + 0.5f * ph;
            boxes[g] = make_float4(x0, y0, x1, y1);
            area[g] = (x1 - x0) * (y1 - y0);
        }
    }
}

// Pass 4: COLUMN-major suppression bit-matrix.
// matT[((wcol*16 + pw)*64) + lane] = word over rows pw*64..pw*64+63 of column
// j = wcol*64+lane: bit e set iff box i=pw*64+e suppresses j (iou>thr && j>i).
// Grid: b(8) x colchunk cc(4, 256 cols) x rowchunk rw(4, 256 rows); 256 thr.
// Thread t owns column j = cc*256+t; rows staged in LDS (broadcast reads).
__global__ __launch_bounds__(256) void k_matT(const float4* __restrict__ boxes,
                                              const float* __restrict__ area,
                                              u64* __restrict__ matT) {
    __shared__ float4 sb[256];
    __shared__ float  sa[256];
    int bid = blockIdx.x;
    int rw = bid & 3, cc = (bid >> 2) & 3, b = bid >> 4;
    int t = threadIdx.x;
    int i0 = rw * 256;
    int in_ = min(256, KTOP - i0);             // valid rows in chunk (232 for rw=3)
    if (t < in_) { sb[t] = boxes[b * KTOP + i0 + t]; sa[t] = area[b * KTOP + i0 + t]; }
    __syncthreads();
    int j = cc * 256 + t;
    u64 w[4] = {0ull, 0ull, 0ull, 0ull};
    if (j < KTOP) {
        float4 bj = boxes[b * KTOP + j];
        float aj = area[b * KTOP + j];
        int emax = j - i0; if (emax > in_) emax = in_;   // rows i < j only
        for (int e = 0; e < emax; ++e) {
            float4 bi = sb[e];
            float lx = fmaxf(bi.x, bj.x), ly = fmaxf(bi.y, bj.y);
            float rx = fminf(bi.z, bj.z), ry = fminf(bi.w, bj.w);
            float ww = fmaxf(rx - lx, 0.0f), hh = fmaxf(ry - ly, 0.0f);
            float inter = ww * hh;
            float iou = inter / (sa[e] + aj - inter + 1e-9f);
            if (iou > 0.5f) w[e >> 6] |= (1ull << (e & 63));
        }
    }
    // write 4 words (always, incl. zeros for j>=KTOP: matT fully initialized)
    int wcol = cc * 4 + (t >> 6);
    int lane = t & 63;
    u64* outp = matT + (size_t)b * (16 * 16 * 64);
#pragma unroll
    for (int lw = 0; lw < 4; ++lw)
        outp[((size_t)wcol * 16 + (rw * 4 + lw)) * 64 + lane] = w[lw];
}

// Pass 5: NMS via column masks. One wave/image; lane l owns columns w*64+l.
// Phase p: (1) within-word-p greedy = fixed-point alive' = init && !(mask &
// ballot(alive)); mask = column's suppressors among word-p rows (strictly
// lower-triangular by construction). Any fixed point of this triangular
// operator is the unique sequential-greedy solution (induction on lane), and
// stabilization propagates in dependency order => terminates (<=64 iters,
// typically ~2-4). (2) cross-word apply for w>p: 1 load + 2 VALU per (w,lane):
// kill iff (column's word-p suppressor mask & aliveSet) != 0. Deferred apply
// is safe: word w's keep bits are only consulted in phase w > p.
__global__ __launch_bounds__(64) void k_nms3(const u64* __restrict__ matT,
                                             u64* __restrict__ keepw) {
    int b = blockIdx.x, l = threadIdx.x;
    const u64* mt = matT + (size_t)b * (16 * 16 * 64);
    u32 keepmask = (l < 40) ? 0xFFFFu : 0x7FFFu;   // col 960+l valid iff l<40
    for (int p = 0; p < 16; ++p) {
        u64 diag = mt[((size_t)p * 16 + p) * 64 + l];
        bool init = (keepmask >> p) & 1u;
        u64 aset = __ballot(init);
        for (;;) {
            bool alive = init && !(diag & aset);
            u64 ns = __ballot(alive);
            if (ns == aset) break;                  // fixed point == greedy
            aset = ns;
        }
        keepmask = (keepmask & ~(1u << p)) | ((u32)((aset >> l) & 1ull) << p);
        for (int w = p + 1; w < 16; ++w) {
            u64 cm = mt[((size_t)w * 16 + p) * 64 + l];
            if (cm & aset) keepmask &= ~(1u << w);
        }
    }
    u64 word = 0;
#pragma unroll
    for (int w = 0; w < 16; ++w) {
        u64 bw = __ballot((keepmask >> w) & 1u);
        if (l == w) word = bw;
    }
    if (l < 16) keepw[b * 16 + l] = word;
}

// Pass 6: final masked outputs (parallel, 32 blocks).
__global__ __launch_bounds__(256) void k_out(const u64* __restrict__ keepw,
                                             const u32* __restrict__ tkey,
                                             const u32* __restrict__ tidx,
                                             const int* __restrict__ cls,
                                             const float4* __restrict__ boxes,
                                             float* __restrict__ out) {
    int gid = blockIdx.x * 256 + threadIdx.x;
    if (gid >= BB * KTOP) return;
    int b = gid / KTOP;
    int k = gid - b * KTOP;
    u64 kwv = keepw[b * 16 + (k >> 6)];
    bool kp = (kwv >> (k & 63)) & 1ull;
    float sc = __uint_as_float(tkey[gid]);
    kp = kp && (sc > 0.0f);
    int cl = cls[(size_t)b * NN + tidx[gid]];
    float4 bx = boxes[gid];
    const int BK = BB * KTOP;
    out[gid] = kp ? (float)cl : -1.0f;                 // out_cls
    out[BK + gid] = kp ? sc : 0.0f;                    // out_scores
    float* ob = out + 2 * BK + (size_t)gid * 4;        // out_boxes
    ob[0] = kp ? bx.x : 0.0f;
    ob[1] = kp ? bx.y : 0.0f;
    ob[2] = kp ? bx.z : 0.0f;
    ob[3] = kp ? bx.w : 0.0f;
    out[6 * BK + gid] = kp ? 1.0f : 0.0f;              // keep
}

extern "C" void kernel_launch(void* const* d_in, const int* in_sizes, int n_in,
                              void* d_out, int out_size, void* d_ws, size_t ws_size,
                              hipStream_t stream) {
    const float* labels  = (const float*)d_in[0];
    const float* codes   = (const float*)d_in[1];
    const float* anchors = (const float*)d_in[2];
    char* ws = (char*)d_ws;
    u32* keys  = (u32*)(ws + OFF_KEYS);
    int* cls   = (int*)(ws + OFF_CLS);
    u32* hist  = (u32*)(ws + OFF_HIST);
    u32* cnt   = (u32*)(ws + OFF_CNT);
    u64* cand  = (u64*)(ws + OFF_CAND);
    u32* tkey  = (u32*)(ws + OFF_TKEY);
    u32* tidx  = (u32*)(ws + OFF_TIDX);
    float4* bx = (float4*)(ws + OFF_BOX);
    float* ar  = (float*)(ws + OFF_AREA);
    u64* mtt   = (u64*)(ws + OFF_MATT);
    u64* kpw   = (u64*)(ws + OFF_KEEP);

    // zero hist + cnt (4640 B; ws re-poisoned 0xAA before every timed launch)
    hipMemsetAsync(ws + OFF_HIST, 0, OFF_CAND - OFF_HIST, stream);

    k_scores_u<<<BB * 196, 256, 0, stream>>>((const float4*)labels, keys, cls, hist);
    k_gather<<<BB * 196, 256, 0, stream>>>(keys, hist, cnt, cand);
    k_sortA<<<BB * 4, 256, 0, stream>>>(cand, cnt);
    k_sortB<<<BB, 512, 0, stream>>>(cand, (const float4*)codes, (const float4*)anchors,
                                    tkey, tidx, bx, ar);
    k_matT<<<BB * 16, 256, 0, stream>>>(bx, ar, mtt);
    k_nms3<<<BB, 64, 0, stream>>>(mtt, kpw);
    k_out<<<(BB * KTOP + 255) / 256, 256, 0, stream>>>(kpw, tkey, tidx, cls, bx, (float*)d_out);
}